// Round 2
// baseline (1284.304 us; speedup 1.0000x reference)
//
#include <hip/hip_runtime.h>

#define N_NODES 100000
#define N_FEATS 256
#define OUT_DIM 64
#define NNZ_X   1280000
#define N_EDGES 1600000
#define NB      391     // ceil(N_NODES/256); bucket = row >> 8
#define CHUNK   4096    // entries per phase-1 block (512 thr, 8/thread)
#define KPT     8
#define CAPX    4352    // X slab capacity (kept-mean 2949, sigma ~54: +25 sigma)
#define CAPA    5120    // A slab capacity (mean 4092, sigma ~64: +16 sigma)

// ---------------- JAX threefry2x32 (partitionable mode, verified R2) ----------------
__device__ __forceinline__ unsigned rotl32(unsigned x, unsigned d) {
    return (x << d) | (x >> (32u - d));
}

__device__ __forceinline__ float jax_uniform_42(unsigned e) {
    unsigned x0 = 0u, x1 = e;
    const unsigned ks0 = 0u, ks1 = 42u, ks2 = 0u ^ 42u ^ 0x1BD11BDAu;
    x0 += ks0; x1 += ks1;
#define TF_R(r) { x0 += x1; x1 = rotl32(x1, r); x1 ^= x0; }
    TF_R(13) TF_R(15) TF_R(26) TF_R(6)
    x0 += ks1; x1 += ks2 + 1u;
    TF_R(17) TF_R(29) TF_R(16) TF_R(24)
    x0 += ks2; x1 += ks0 + 2u;
    TF_R(13) TF_R(15) TF_R(26) TF_R(6)
    x0 += ks0; x1 += ks1 + 3u;
    TF_R(17) TF_R(29) TF_R(16) TF_R(24)
    x0 += ks1; x1 += ks2 + 4u;
    TF_R(13) TF_R(15) TF_R(26) TF_R(6)
    x0 += ks2; x1 += ks0 + 5u;
#undef TF_R
    unsigned bits = x0 ^ x1;
    return __uint_as_float((bits >> 9) | 0x3f800000u) - 1.0f;
}

__device__ __forceinline__ bool keep_42(unsigned e) {
    float u = jax_uniform_42(e);
    return floorf(0.9f + u) != 0.0f;
}

// f32 -> bf16 round-to-nearest-even
__device__ __forceinline__ unsigned short f32_bf16(float f) {
    unsigned bits = __float_as_uint(f);
    return (unsigned short)((bits + 0x7fffu + ((bits >> 16) & 1u)) >> 16);
}

__device__ __forceinline__ unsigned pack_bf16x2(float lo, float hi) {
    return (unsigned)f32_bf16(lo) | ((unsigned)f32_bf16(hi) << 16);
}

__device__ __forceinline__ float bflo(unsigned u) { return __uint_as_float(u << 16); }
__device__ __forceinline__ float bfhi(unsigned u) { return __uint_as_float(u & 0xffff0000u); }

// ---------------- phase 1 (R14 verbatim): single-load payload staging ----------
__global__ __launch_bounds__(512) void phase1(
        const float* __restrict__ fvals, const int* __restrict__ frows,
        const int* __restrict__ fcols,
        const float* __restrict__ avals, const int* __restrict__ arows,
        const int* __restrict__ acols,
        int* __restrict__ bcur_x, int* __restrict__ bcur_a,
        float2* __restrict__ gx, float2* __restrict__ ga) {
    const int isA = blockIdx.y;
    const float* vals = isA ? avals : fvals;
    const int* rows   = isA ? arows : frows;
    const int* cols   = isA ? acols : fcols;
    int* bcur         = isA ? bcur_a : bcur_x;
    float2* dst       = isA ? ga : gx;
    const unsigned cap = isA ? CAPA : CAPX;
    const unsigned n  = isA ? N_EDGES : NNZ_X;

    unsigned t = threadIdx.x;
    unsigned base = blockIdx.x * CHUNK;
    if (base >= n) return;

    __shared__ int cnt[512];
    __shared__ int start[512];
    __shared__ int cur[512];
    __shared__ int gbase[NB];
    __shared__ int wtot[8];
    __shared__ int s_nvalid;
    __shared__ unsigned long long payload[CHUNK];   // 32 KB: (valbits<<32)|(col<<8)|rowlow
    __shared__ unsigned short bkt[CHUNK];           // 8 KB

    int   rcache[KPT];
    float vcache[KPT];
    int   ccache[KPT];

    cnt[t] = 0;
    __syncthreads();
    #pragma unroll
    for (int k = 0; k < KPT; k++) {
        unsigned i = base + k * 512u + t;
        int r = -1;
        if (i < n) {
            int rr = rows[i];
            float v = vals[i];          // coalesced, up-front
            int   c = cols[i];          // coalesced, up-front
            if (isA || keep_42(i)) {
                r = rr;
                vcache[k] = isA ? v : v * (float)(1.0 / 0.9);
                ccache[k] = c;
            }
        }
        rcache[k] = r;
        if (r >= 0) atomicAdd(&cnt[(unsigned)r >> 8], 1);
    }
    __syncthreads();
    // 8-wave shfl scan over 512 bins (2 barriers total)
    unsigned lane = t & 63u, wid = t >> 6;
    int binv = cnt[t];
    int inc = binv;
    #pragma unroll
    for (int d = 1; d < 64; d <<= 1) {
        int v = __shfl_up(inc, d, 64);
        if (lane >= (unsigned)d) inc += v;
    }
    if (lane == 63u) wtot[wid] = inc;
    __syncthreads();
    int offw = 0;
    #pragma unroll
    for (int w = 0; w < 8; w++) if ((unsigned)w < wid) offw += wtot[w];
    int excl = offw + inc - binv;
    start[t] = excl;
    cur[t]   = excl;
    if (t == 511u) s_nvalid = excl + binv;
    if (t < NB) {
        int cb = cnt[t];
        if (cb > 0) gbase[t] = atomicAdd(&bcur[t], cb);
    }
    __syncthreads();
    int n_valid = s_nvalid;
    #pragma unroll
    for (int k = 0; k < KPT; k++) {
        int r = rcache[k];
        if (r >= 0) {
            unsigned b = (unsigned)r >> 8;
            int p = atomicAdd(&cur[b], 1);
            unsigned packed = ((unsigned)ccache[k] << 8) | ((unsigned)r & 255u);
            payload[p] = ((unsigned long long)__float_as_uint(vcache[k]) << 32) | packed;
            bkt[p] = (unsigned short)b;
        }
    }
    __syncthreads();
    #pragma unroll
    for (int k = 0; k < KPT; k++) {
        int sidx = k * 512 + (int)t;
        if (sidx < n_valid) {
            unsigned b = bkt[sidx];
            unsigned long long m = payload[sidx];
            float2 e;
            e.x = __uint_as_float((unsigned)(m >> 32));
            e.y = __int_as_float((int)(unsigned)m);
            dst[(size_t)b * cap + gbase[b] + (sidx - start[b])] = e;
        }
    }
}

// ---------------- SpMM1 scatter (R15): unsorted slab -> ds_add_f32 LDS acc ----
// One block per 256-row bucket. acc[256][64] f32 = exactly 64 KB, XOR-swizzled
// per row (addr = (r<<6)|(d^(r&31))) to break the stride-64 16-way bank alias.
// Replaces the entire X half of sort_stage: 2 barriers instead of 6+.
__global__ __launch_bounds__(512) void spmm1_scatter(
        const int* __restrict__ bcur_x, const float2* __restrict__ gx,
        const float* __restrict__ W, unsigned short* __restrict__ xw) {
    __shared__ float acc[256 * 64];    // 64 KB
    unsigned t = threadIdx.x;
    unsigned b = blockIdx.x;
    int cnt = bcur_x[b];
    const float2* src = gx + (size_t)b * CAPX;
    float4* accv = (float4*)acc;
    for (int i = (int)t; i < 4096; i += 512)
        accv[i] = make_float4(0.f, 0.f, 0.f, 0.f);
    __syncthreads();

    unsigned g = t >> 3, sub = t & 7u;       // 64 groups x 8 dim-octet lanes
    const float4* W4 = (const float4*)W;     // W row = 16 float4
    unsigned d0 = sub * 8u;
    int i = (int)g;
    for (; i + 64 < cnt; i += 128) {         // 2-deep: two gathers in flight
        float2 e0 = src[i], e1 = src[i + 64];
        unsigned p0 = (unsigned)__float_as_int(e0.y);
        unsigned p1 = (unsigned)__float_as_int(e1.y);
        float4 w00 = W4[(p0 >> 8) * 16u + sub * 2u];
        float4 w01 = W4[(p0 >> 8) * 16u + sub * 2u + 1u];
        float4 w10 = W4[(p1 >> 8) * 16u + sub * 2u];
        float4 w11 = W4[(p1 >> 8) * 16u + sub * 2u + 1u];
        float v0 = e0.x, v1 = e1.x;
        unsigned r0 = p0 & 255u, r1 = p1 & 255u;
        unsigned b0 = r0 << 6, x0 = r0 & 31u;
        unsigned b1 = r1 << 6, x1 = r1 & 31u;
        atomicAdd(&acc[b0 | ((d0 + 0u) ^ x0)], v0 * w00.x);
        atomicAdd(&acc[b0 | ((d0 + 1u) ^ x0)], v0 * w00.y);
        atomicAdd(&acc[b0 | ((d0 + 2u) ^ x0)], v0 * w00.z);
        atomicAdd(&acc[b0 | ((d0 + 3u) ^ x0)], v0 * w00.w);
        atomicAdd(&acc[b0 | ((d0 + 4u) ^ x0)], v0 * w01.x);
        atomicAdd(&acc[b0 | ((d0 + 5u) ^ x0)], v0 * w01.y);
        atomicAdd(&acc[b0 | ((d0 + 6u) ^ x0)], v0 * w01.z);
        atomicAdd(&acc[b0 | ((d0 + 7u) ^ x0)], v0 * w01.w);
        atomicAdd(&acc[b1 | ((d0 + 0u) ^ x1)], v1 * w10.x);
        atomicAdd(&acc[b1 | ((d0 + 1u) ^ x1)], v1 * w10.y);
        atomicAdd(&acc[b1 | ((d0 + 2u) ^ x1)], v1 * w10.z);
        atomicAdd(&acc[b1 | ((d0 + 3u) ^ x1)], v1 * w10.w);
        atomicAdd(&acc[b1 | ((d0 + 4u) ^ x1)], v1 * w11.x);
        atomicAdd(&acc[b1 | ((d0 + 5u) ^ x1)], v1 * w11.y);
        atomicAdd(&acc[b1 | ((d0 + 6u) ^ x1)], v1 * w11.z);
        atomicAdd(&acc[b1 | ((d0 + 7u) ^ x1)], v1 * w11.w);
    }
    if (i < cnt) {
        float2 e0 = src[i];
        unsigned p0 = (unsigned)__float_as_int(e0.y);
        float4 w00 = W4[(p0 >> 8) * 16u + sub * 2u];
        float4 w01 = W4[(p0 >> 8) * 16u + sub * 2u + 1u];
        float v0 = e0.x;
        unsigned r0 = p0 & 255u;
        unsigned b0 = r0 << 6, x0 = r0 & 31u;
        atomicAdd(&acc[b0 | ((d0 + 0u) ^ x0)], v0 * w00.x);
        atomicAdd(&acc[b0 | ((d0 + 1u) ^ x0)], v0 * w00.y);
        atomicAdd(&acc[b0 | ((d0 + 2u) ^ x0)], v0 * w00.z);
        atomicAdd(&acc[b0 | ((d0 + 3u) ^ x0)], v0 * w00.w);
        atomicAdd(&acc[b0 | ((d0 + 4u) ^ x0)], v0 * w01.x);
        atomicAdd(&acc[b0 | ((d0 + 5u) ^ x0)], v0 * w01.y);
        atomicAdd(&acc[b0 | ((d0 + 6u) ^ x0)], v0 * w01.z);
        atomicAdd(&acc[b0 | ((d0 + 7u) ^ x0)], v0 * w01.w);
    }
    __syncthreads();
    // writeout: bf16, one uint4 (8 dims) per item
    uint4* xw8 = (uint4*)xw;
    unsigned row0 = b << 8;
    for (int it = (int)t; it < 2048; it += 512) {
        unsigned r = (unsigned)it >> 3, s = (unsigned)it & 7u;
        unsigned grow = row0 + r;
        if (grow < N_NODES) {
            unsigned bs = r << 6, x = r & 31u, d = s * 8u;
            float f0 = acc[bs | ((d + 0u) ^ x)];
            float f1 = acc[bs | ((d + 1u) ^ x)];
            float f2 = acc[bs | ((d + 2u) ^ x)];
            float f3 = acc[bs | ((d + 3u) ^ x)];
            float f4 = acc[bs | ((d + 4u) ^ x)];
            float f5 = acc[bs | ((d + 5u) ^ x)];
            float f6 = acc[bs | ((d + 6u) ^ x)];
            float f7 = acc[bs | ((d + 7u) ^ x)];
            uint4 o;
            o.x = pack_bf16x2(f0, f1);
            o.y = pack_bf16x2(f2, f3);
            o.z = pack_bf16x2(f4, f5);
            o.w = pack_bf16x2(f6, f7);
            xw8[(size_t)grow * 8u + s] = o;
        }
    }
}

// ---------------- SpMM2 scatter + ReLU (R15): unsorted slab -> ds_add_f32 ----
// Same structure; gathers xw rows (uint4 = 8 bf16 dims) instead of W.
// Replaces sort_stage's A half AND the old spmm2 kernel (no sorted-ga
// round-trip, no rs_a).
__global__ __launch_bounds__(512) void spmm2_scatter(
        const int* __restrict__ bcur_a, const float2* __restrict__ ga,
        const unsigned short* __restrict__ xw, float* __restrict__ out) {
    __shared__ float acc[256 * 64];    // 64 KB
    unsigned t = threadIdx.x;
    unsigned b = blockIdx.x;
    int cnt = bcur_a[b];
    const float2* src = ga + (size_t)b * CAPA;
    float4* accv = (float4*)acc;
    for (int i = (int)t; i < 4096; i += 512)
        accv[i] = make_float4(0.f, 0.f, 0.f, 0.f);
    __syncthreads();

    unsigned g = t >> 3, sub = t & 7u;
    const uint4* xw8 = (const uint4*)xw;     // row stride = 8 uint4 (128B)
    unsigned d0 = sub * 8u;
    int i = (int)g;
    for (; i + 64 < cnt; i += 128) {
        float2 e0 = src[i], e1 = src[i + 64];
        unsigned p0 = (unsigned)__float_as_int(e0.y);
        unsigned p1 = (unsigned)__float_as_int(e1.y);
        uint4 u0 = xw8[(p0 >> 8) * 8u + sub];
        uint4 u1 = xw8[(p1 >> 8) * 8u + sub];
        float v0 = e0.x, v1 = e1.x;
        unsigned r0 = p0 & 255u, r1 = p1 & 255u;
        unsigned b0 = r0 << 6, x0 = r0 & 31u;
        unsigned b1 = r1 << 6, x1 = r1 & 31u;
        atomicAdd(&acc[b0 | ((d0 + 0u) ^ x0)], v0 * bflo(u0.x));
        atomicAdd(&acc[b0 | ((d0 + 1u) ^ x0)], v0 * bfhi(u0.x));
        atomicAdd(&acc[b0 | ((d0 + 2u) ^ x0)], v0 * bflo(u0.y));
        atomicAdd(&acc[b0 | ((d0 + 3u) ^ x0)], v0 * bfhi(u0.y));
        atomicAdd(&acc[b0 | ((d0 + 4u) ^ x0)], v0 * bflo(u0.z));
        atomicAdd(&acc[b0 | ((d0 + 5u) ^ x0)], v0 * bfhi(u0.z));
        atomicAdd(&acc[b0 | ((d0 + 6u) ^ x0)], v0 * bflo(u0.w));
        atomicAdd(&acc[b0 | ((d0 + 7u) ^ x0)], v0 * bfhi(u0.w));
        atomicAdd(&acc[b1 | ((d0 + 0u) ^ x1)], v1 * bflo(u1.x));
        atomicAdd(&acc[b1 | ((d0 + 1u) ^ x1)], v1 * bfhi(u1.x));
        atomicAdd(&acc[b1 | ((d0 + 2u) ^ x1)], v1 * bflo(u1.y));
        atomicAdd(&acc[b1 | ((d0 + 3u) ^ x1)], v1 * bfhi(u1.y));
        atomicAdd(&acc[b1 | ((d0 + 4u) ^ x1)], v1 * bflo(u1.z));
        atomicAdd(&acc[b1 | ((d0 + 5u) ^ x1)], v1 * bfhi(u1.z));
        atomicAdd(&acc[b1 | ((d0 + 6u) ^ x1)], v1 * bflo(u1.w));
        atomicAdd(&acc[b1 | ((d0 + 7u) ^ x1)], v1 * bfhi(u1.w));
    }
    if (i < cnt) {
        float2 e0 = src[i];
        unsigned p0 = (unsigned)__float_as_int(e0.y);
        uint4 u0 = xw8[(p0 >> 8) * 8u + sub];
        float v0 = e0.x;
        unsigned r0 = p0 & 255u;
        unsigned b0 = r0 << 6, x0 = r0 & 31u;
        atomicAdd(&acc[b0 | ((d0 + 0u) ^ x0)], v0 * bflo(u0.x));
        atomicAdd(&acc[b0 | ((d0 + 1u) ^ x0)], v0 * bfhi(u0.x));
        atomicAdd(&acc[b0 | ((d0 + 2u) ^ x0)], v0 * bflo(u0.y));
        atomicAdd(&acc[b0 | ((d0 + 3u) ^ x0)], v0 * bfhi(u0.y));
        atomicAdd(&acc[b0 | ((d0 + 4u) ^ x0)], v0 * bflo(u0.z));
        atomicAdd(&acc[b0 | ((d0 + 5u) ^ x0)], v0 * bfhi(u0.z));
        atomicAdd(&acc[b0 | ((d0 + 6u) ^ x0)], v0 * bflo(u0.w));
        atomicAdd(&acc[b0 | ((d0 + 7u) ^ x0)], v0 * bfhi(u0.w));
    }
    __syncthreads();
    // writeout with ReLU: float4 per item
    unsigned row0 = b << 8;
    for (int it = (int)t; it < 4096; it += 512) {
        unsigned r = (unsigned)it >> 4, q = (unsigned)it & 15u;
        unsigned grow = row0 + r;
        if (grow < N_NODES) {
            unsigned bs = r << 6, x = r & 31u, d = q * 4u;
            float4 o;
            o.x = fmaxf(acc[bs | ((d + 0u) ^ x)], 0.f);
            o.y = fmaxf(acc[bs | ((d + 1u) ^ x)], 0.f);
            o.z = fmaxf(acc[bs | ((d + 2u) ^ x)], 0.f);
            o.w = fmaxf(acc[bs | ((d + 3u) ^ x)], 0.f);
            ((float4*)out)[(size_t)grow * 16u + q] = o;
        }
    }
}

extern "C" void kernel_launch(void* const* d_in, const int* in_sizes, int n_in,
                              void* d_out, int out_size, void* d_ws, size_t ws_size,
                              hipStream_t stream) {
    const float* feat_values = (const float*)d_in[0];
    const float* W           = (const float*)d_in[1];
    const float* adj_values  = (const float*)d_in[2];
    const int*   feat_rows   = (const int*)d_in[3];
    const int*   feat_cols   = (const int*)d_in[4];
    const int*   adj_rows    = (const int*)d_in[5];
    const int*   adj_cols    = (const int*)d_in[6];
    float* out = (float*)d_out;

    // ---- workspace layout (bytes) ----
    char* ws = (char*)d_ws;
    int* bcur_x = (int*)(ws + 0);
    int* bcur_a = (int*)(ws + 2048);
    float2* gx  = (float2*)(ws + 204800);
    float2* ga  = (float2*)(ws + 13817856);
    unsigned short* xw = (unsigned short*)(ws + 29833216);

    hipMemsetAsync(ws, 0, 4096, stream);    // bucket cursors

    dim3 gp1((N_EDGES + CHUNK - 1) / CHUNK, 2);
    phase1<<<gp1, 512, 0, stream>>>(feat_values, feat_rows, feat_cols,
                                    adj_values, adj_rows, adj_cols,
                                    bcur_x, bcur_a, gx, ga);
    spmm1_scatter<<<NB, 512, 0, stream>>>(bcur_x, gx, W, xw);
    spmm2_scatter<<<NB, 512, 0, stream>>>(bcur_a, ga, xw, out);
}

// Round 3
// 179.911 us; speedup vs baseline: 7.1386x; 7.1386x over previous
//
#include <hip/hip_runtime.h>

#define N_NODES 100000
#define N_FEATS 256
#define OUT_DIM 64
#define NNZ_X   1280000
#define N_EDGES 1600000
#define NB      391     // ceil(N_NODES/256); bucket = row >> 8
#define CHUNK   4096    // entries per phase-1 block (512 thr, 8/thread)
#define KPT     8
#define CAPX    4352    // X slab capacity (kept-mean 2949, sigma ~54: +25 sigma)
#define CAPA    5120    // A slab capacity (mean 4092, sigma ~64: +16 sigma)

// ---------------- JAX threefry2x32 (partitionable mode, verified R2) ----------------
__device__ __forceinline__ unsigned rotl32(unsigned x, unsigned d) {
    return (x << d) | (x >> (32u - d));
}

__device__ __forceinline__ float jax_uniform_42(unsigned e) {
    unsigned x0 = 0u, x1 = e;
    const unsigned ks0 = 0u, ks1 = 42u, ks2 = 0u ^ 42u ^ 0x1BD11BDAu;
    x0 += ks0; x1 += ks1;
#define TF_R(r) { x0 += x1; x1 = rotl32(x1, r); x1 ^= x0; }
    TF_R(13) TF_R(15) TF_R(26) TF_R(6)
    x0 += ks1; x1 += ks2 + 1u;
    TF_R(17) TF_R(29) TF_R(16) TF_R(24)
    x0 += ks2; x1 += ks0 + 2u;
    TF_R(13) TF_R(15) TF_R(26) TF_R(6)
    x0 += ks0; x1 += ks1 + 3u;
    TF_R(17) TF_R(29) TF_R(16) TF_R(24)
    x0 += ks1; x1 += ks2 + 4u;
    TF_R(13) TF_R(15) TF_R(26) TF_R(6)
    x0 += ks2; x1 += ks0 + 5u;
#undef TF_R
    unsigned bits = x0 ^ x1;
    return __uint_as_float((bits >> 9) | 0x3f800000u) - 1.0f;
}

__device__ __forceinline__ bool keep_42(unsigned e) {
    float u = jax_uniform_42(e);
    return floorf(0.9f + u) != 0.0f;
}

// f32 -> bf16 round-to-nearest-even
__device__ __forceinline__ unsigned short f32_bf16(float f) {
    unsigned bits = __float_as_uint(f);
    return (unsigned short)((bits + 0x7fffu + ((bits >> 16) & 1u)) >> 16);
}

__device__ __forceinline__ float bflo(unsigned u) { return __uint_as_float(u << 16); }
__device__ __forceinline__ float bfhi(unsigned u) { return __uint_as_float(u & 0xffff0000u); }

// ---------------- phase 1 (R14 verbatim): single-load payload staging ----------
__global__ __launch_bounds__(512) void phase1(
        const float* __restrict__ fvals, const int* __restrict__ frows,
        const int* __restrict__ fcols,
        const float* __restrict__ avals, const int* __restrict__ arows,
        const int* __restrict__ acols,
        int* __restrict__ bcur_x, int* __restrict__ bcur_a,
        float2* __restrict__ gx, float2* __restrict__ ga) {
    const int isA = blockIdx.y;
    const float* vals = isA ? avals : fvals;
    const int* rows   = isA ? arows : frows;
    const int* cols   = isA ? acols : fcols;
    int* bcur         = isA ? bcur_a : bcur_x;
    float2* dst       = isA ? ga : gx;
    const unsigned cap = isA ? CAPA : CAPX;
    const unsigned n  = isA ? N_EDGES : NNZ_X;

    unsigned t = threadIdx.x;
    unsigned base = blockIdx.x * CHUNK;
    if (base >= n) return;

    __shared__ int cnt[512];
    __shared__ int start[512];
    __shared__ int cur[512];
    __shared__ int gbase[NB];
    __shared__ int wtot[8];
    __shared__ int s_nvalid;
    __shared__ unsigned long long payload[CHUNK];   // 32 KB: (valbits<<32)|(col<<8)|rowlow
    __shared__ unsigned short bkt[CHUNK];           // 8 KB

    int   rcache[KPT];
    float vcache[KPT];
    int   ccache[KPT];

    cnt[t] = 0;
    __syncthreads();
    #pragma unroll
    for (int k = 0; k < KPT; k++) {
        unsigned i = base + k * 512u + t;
        int r = -1;
        if (i < n) {
            int rr = rows[i];
            float v = vals[i];          // coalesced, up-front
            int   c = cols[i];          // coalesced, up-front
            if (isA || keep_42(i)) {
                r = rr;
                vcache[k] = isA ? v : v * (float)(1.0 / 0.9);
                ccache[k] = c;
            }
        }
        rcache[k] = r;
        if (r >= 0) atomicAdd(&cnt[(unsigned)r >> 8], 1);
    }
    __syncthreads();
    // 8-wave shfl scan over 512 bins (2 barriers total)
    unsigned lane = t & 63u, wid = t >> 6;
    int binv = cnt[t];
    int inc = binv;
    #pragma unroll
    for (int d = 1; d < 64; d <<= 1) {
        int v = __shfl_up(inc, d, 64);
        if (lane >= (unsigned)d) inc += v;
    }
    if (lane == 63u) wtot[wid] = inc;
    __syncthreads();
    int offw = 0;
    #pragma unroll
    for (int w = 0; w < 8; w++) if ((unsigned)w < wid) offw += wtot[w];
    int excl = offw + inc - binv;
    start[t] = excl;
    cur[t]   = excl;
    if (t == 511u) s_nvalid = excl + binv;
    if (t < NB) {
        int cb = cnt[t];
        if (cb > 0) gbase[t] = atomicAdd(&bcur[t], cb);
    }
    __syncthreads();
    int n_valid = s_nvalid;
    #pragma unroll
    for (int k = 0; k < KPT; k++) {
        int r = rcache[k];
        if (r >= 0) {
            unsigned b = (unsigned)r >> 8;
            int p = atomicAdd(&cur[b], 1);
            unsigned packed = ((unsigned)ccache[k] << 8) | ((unsigned)r & 255u);
            payload[p] = ((unsigned long long)__float_as_uint(vcache[k]) << 32) | packed;
            bkt[p] = (unsigned short)b;
        }
    }
    __syncthreads();
    #pragma unroll
    for (int k = 0; k < KPT; k++) {
        int sidx = k * 512 + (int)t;
        if (sidx < n_valid) {
            unsigned b = bkt[sidx];
            unsigned long long m = payload[sidx];
            float2 e;
            e.x = __uint_as_float((unsigned)(m >> 32));
            e.y = __int_as_float((int)(unsigned)m);
            dst[(size_t)b * cap + gbase[b] + (sidx - start[b])] = e;
        }
    }
}

// ---------------- sort_x_spmm1 (R16): X bucket sort in LDS + SpMM1 ------------
// 1024 threads (16 waves) for latency hiding at 391 blocks (~1.5/CU).
// Register-caches the slab (one global pass instead of two).
__global__ __launch_bounds__(1024) void sort_x_spmm1(
        const int* __restrict__ bcur_x, const float2* __restrict__ gx,
        const float* __restrict__ W, unsigned short* __restrict__ xw) {
    __shared__ float2 ent[CAPX];       // 34.8 KB
    __shared__ int hist[256];
    __shared__ int starts[256];
    __shared__ int cursor[256];
    __shared__ int wtot[4];
    unsigned t = threadIdx.x;
    unsigned wid = t >> 6, lane = t & 63u;
    unsigned b = blockIdx.x;
    int cnt = bcur_x[b];
    const float2* src = gx + (size_t)b * CAPX;

    if (t < 256) hist[t] = 0;
    __syncthreads();
    float2 ec[4];
    #pragma unroll
    for (int k = 0; k < 4; k++) {
        int i = k * 1024 + (int)t;
        if (i < cnt) {
            float2 e = src[i];
            ec[k] = e;
            atomicAdd(&hist[((unsigned)__float_as_int(e.y)) & 255u], 1);
        }
    }
    for (int i = 4096 + (int)t; i < cnt; i += 1024)   // overflow guard (cnt>4096: ~never)
        atomicAdd(&hist[((unsigned)__float_as_int(src[i].y)) & 255u], 1);
    __syncthreads();
    int inc = 0, binv = 0;
    if (wid < 4u) {
        unsigned bin = wid * 64u + lane;
        binv = hist[bin];
        inc = binv;
        #pragma unroll
        for (int d = 1; d < 64; d <<= 1) {
            int v = __shfl_up(inc, d, 64);
            if (lane >= (unsigned)d) inc += v;
        }
        if (lane == 63u) wtot[wid] = inc;
    }
    __syncthreads();
    if (wid < 4u) {
        int offw = 0;
        #pragma unroll
        for (int w = 0; w < 4; w++) if ((unsigned)w < wid) offw += wtot[w];
        unsigned bin = wid * 64u + lane;
        int excl = inc - binv + offw;
        starts[bin] = excl;
        cursor[bin] = excl;
    }
    __syncthreads();
    #pragma unroll
    for (int k = 0; k < 4; k++) {
        int i = k * 1024 + (int)t;
        if (i < cnt) {
            float2 e = ec[k];
            int pos = atomicAdd(&cursor[((unsigned)__float_as_int(e.y)) & 255u], 1);
            ent[pos] = e;
        }
    }
    for (int i = 4096 + (int)t; i < cnt; i += 1024) {
        float2 e = src[i];
        int pos = atomicAdd(&cursor[((unsigned)__float_as_int(e.y)) & 255u], 1);
        ent[pos] = e;
    }
    __syncthreads();
    // SpMM1: 16 waves x 16 rows; quarter-wave float4 W gathers
    unsigned quarter = lane >> 4, sub = lane & 15u;
    const float4* W4 = (const float4*)W;       // row stride 16 float4
    ushort4* xw4 = (ushort4*)xw;               // row stride 16 ushort4
    for (unsigned r = wid; r < 256u; r += 16u) {
        int s0 = starts[r];
        int s1 = (r == 255u) ? cnt : starts[r + 1];
        float4 acc[4];
        #pragma unroll
        for (int j = 0; j < 4; j++) { acc[j].x = acc[j].y = acc[j].z = acc[j].w = 0.0f; }
        int p = s0;
        for (; p + 16 <= s1; p += 16) {
            float2 e[4];
            #pragma unroll
            for (int j = 0; j < 4; j++) e[j] = ent[p + 4 * quarter + j];
            float4 w[4];
            #pragma unroll
            for (int j = 0; j < 4; j++)
                w[j] = W4[(((unsigned)__float_as_int(e[j].y)) >> 8) * 16u + sub];
            #pragma unroll
            for (int j = 0; j < 4; j++) {
                acc[j].x = fmaf(e[j].x, w[j].x, acc[j].x);
                acc[j].y = fmaf(e[j].x, w[j].y, acc[j].y);
                acc[j].z = fmaf(e[j].x, w[j].z, acc[j].z);
                acc[j].w = fmaf(e[j].x, w[j].w, acc[j].w);
            }
        }
        for (int q = p + (int)quarter; q < s1; q += 4) {
            float2 e = ent[q];
            float4 w = W4[(((unsigned)__float_as_int(e.y)) >> 8) * 16u + sub];
            acc[0].x = fmaf(e.x, w.x, acc[0].x);
            acc[0].y = fmaf(e.x, w.y, acc[0].y);
            acc[0].z = fmaf(e.x, w.z, acc[0].z);
            acc[0].w = fmaf(e.x, w.w, acc[0].w);
        }
        float ax = (acc[0].x + acc[1].x) + (acc[2].x + acc[3].x);
        float ay = (acc[0].y + acc[1].y) + (acc[2].y + acc[3].y);
        float az = (acc[0].z + acc[1].z) + (acc[2].z + acc[3].z);
        float aw = (acc[0].w + acc[1].w) + (acc[2].w + acc[3].w);
        ax += __shfl(ax, (int)(lane ^ 16u), 64);
        ay += __shfl(ay, (int)(lane ^ 16u), 64);
        az += __shfl(az, (int)(lane ^ 16u), 64);
        aw += __shfl(aw, (int)(lane ^ 16u), 64);
        ax += __shfl(ax, (int)(lane ^ 32u), 64);
        ay += __shfl(ay, (int)(lane ^ 32u), 64);
        az += __shfl(az, (int)(lane ^ 32u), 64);
        aw += __shfl(aw, (int)(lane ^ 32u), 64);
        unsigned grow = (b << 8) + r;
        if (quarter == 0 && grow < N_NODES) {
            ushort4 o;
            o.x = f32_bf16(ax); o.y = f32_bf16(ay);
            o.z = f32_bf16(az); o.w = f32_bf16(aw);
            xw4[(size_t)grow * 16u + sub] = o;
        }
    }
}

// ---------------- sort_a_spmm2 (R16): A bucket sort in LDS + SpMM2 + ReLU -----
// Replaces the A half of sort_stage AND the spmm2 kernel: no sorted-ga global
// write-back/re-read (saves ~26 MB + a dispatch). Oct-scheme uint4 xw gathers.
__global__ __launch_bounds__(1024) void sort_a_spmm2(
        const int* __restrict__ bcur_a, const float2* __restrict__ ga,
        const unsigned short* __restrict__ xw, float* __restrict__ out) {
    __shared__ float2 ent[CAPA];       // 40 KB
    __shared__ int hist[256];
    __shared__ int starts[256];
    __shared__ int cursor[256];
    __shared__ int wtot[4];
    unsigned t = threadIdx.x;
    unsigned wid = t >> 6, lane = t & 63u;
    unsigned b = blockIdx.x;
    int cnt = bcur_a[b];
    const float2* src = ga + (size_t)b * CAPA;

    if (t < 256) hist[t] = 0;
    __syncthreads();
    float2 ec[5];
    #pragma unroll
    for (int k = 0; k < 5; k++) {
        int i = k * 1024 + (int)t;
        if (i < cnt) {
            float2 e = src[i];
            ec[k] = e;
            atomicAdd(&hist[((unsigned)__float_as_int(e.y)) & 255u], 1);
        }
    }
    __syncthreads();
    int inc = 0, binv = 0;
    if (wid < 4u) {
        unsigned bin = wid * 64u + lane;
        binv = hist[bin];
        inc = binv;
        #pragma unroll
        for (int d = 1; d < 64; d <<= 1) {
            int v = __shfl_up(inc, d, 64);
            if (lane >= (unsigned)d) inc += v;
        }
        if (lane == 63u) wtot[wid] = inc;
    }
    __syncthreads();
    if (wid < 4u) {
        int offw = 0;
        #pragma unroll
        for (int w = 0; w < 4; w++) if ((unsigned)w < wid) offw += wtot[w];
        unsigned bin = wid * 64u + lane;
        int excl = inc - binv + offw;
        starts[bin] = excl;
        cursor[bin] = excl;
    }
    __syncthreads();
    #pragma unroll
    for (int k = 0; k < 5; k++) {
        int i = k * 1024 + (int)t;
        if (i < cnt) {
            float2 e = ec[k];
            int pos = atomicAdd(&cursor[((unsigned)__float_as_int(e.y)) & 255u], 1);
            ent[pos] = e;
        }
    }
    __syncthreads();
    // SpMM2: 16 waves x 16 rows; oct-scheme (8 edge slots x 8 dim-octets)
    unsigned oct = lane >> 3, sub = lane & 7u;
    const uint4* xw8 = (const uint4*)xw;   // row stride = 8 uint4 (128B)
    for (unsigned r = wid; r < 256u; r += 16u) {
        int s0 = starts[r];
        int s1 = (r == 255u) ? cnt : starts[r + 1];
        float acc[8];
        #pragma unroll
        for (int j = 0; j < 8; j++) acc[j] = 0.0f;
        int p = s0 + (int)oct;
        for (; p + 8 < s1; p += 16) {
            float2 e0 = ent[p];
            float2 e1 = ent[p + 8];
            uint4 u0 = xw8[(((unsigned)__float_as_int(e0.y)) >> 8) * 8u + sub];
            uint4 u1 = xw8[(((unsigned)__float_as_int(e1.y)) >> 8) * 8u + sub];
            float v0 = e0.x, v1 = e1.x;
            acc[0] = fmaf(v0, bflo(u0.x), acc[0]);
            acc[1] = fmaf(v0, bfhi(u0.x), acc[1]);
            acc[2] = fmaf(v0, bflo(u0.y), acc[2]);
            acc[3] = fmaf(v0, bfhi(u0.y), acc[3]);
            acc[4] = fmaf(v0, bflo(u0.z), acc[4]);
            acc[5] = fmaf(v0, bfhi(u0.z), acc[5]);
            acc[6] = fmaf(v0, bflo(u0.w), acc[6]);
            acc[7] = fmaf(v0, bfhi(u0.w), acc[7]);
            acc[0] = fmaf(v1, bflo(u1.x), acc[0]);
            acc[1] = fmaf(v1, bfhi(u1.x), acc[1]);
            acc[2] = fmaf(v1, bflo(u1.y), acc[2]);
            acc[3] = fmaf(v1, bfhi(u1.y), acc[3]);
            acc[4] = fmaf(v1, bflo(u1.z), acc[4]);
            acc[5] = fmaf(v1, bfhi(u1.z), acc[5]);
            acc[6] = fmaf(v1, bflo(u1.w), acc[6]);
            acc[7] = fmaf(v1, bfhi(u1.w), acc[7]);
        }
        if (p < s1) {
            float2 e = ent[p];
            uint4 u = xw8[(((unsigned)__float_as_int(e.y)) >> 8) * 8u + sub];
            float v = e.x;
            acc[0] = fmaf(v, bflo(u.x), acc[0]);
            acc[1] = fmaf(v, bfhi(u.x), acc[1]);
            acc[2] = fmaf(v, bflo(u.y), acc[2]);
            acc[3] = fmaf(v, bfhi(u.y), acc[3]);
            acc[4] = fmaf(v, bflo(u.z), acc[4]);
            acc[5] = fmaf(v, bfhi(u.z), acc[5]);
            acc[6] = fmaf(v, bflo(u.w), acc[6]);
            acc[7] = fmaf(v, bfhi(u.w), acc[7]);
        }
        #pragma unroll
        for (int j = 0; j < 8; j++) {
            acc[j] += __shfl_xor(acc[j], 8, 64);
            acc[j] += __shfl_xor(acc[j], 16, 64);
            acc[j] += __shfl_xor(acc[j], 32, 64);
        }
        unsigned grow = (b << 8) + r;
        if (oct == 0 && grow < N_NODES) {
            float4 o0, o1;
            o0.x = fmaxf(acc[0], 0.0f);
            o0.y = fmaxf(acc[1], 0.0f);
            o0.z = fmaxf(acc[2], 0.0f);
            o0.w = fmaxf(acc[3], 0.0f);
            o1.x = fmaxf(acc[4], 0.0f);
            o1.y = fmaxf(acc[5], 0.0f);
            o1.z = fmaxf(acc[6], 0.0f);
            o1.w = fmaxf(acc[7], 0.0f);
            float4* op = (float4*)(out + (size_t)grow * 64u + sub * 8u);
            op[0] = o0;
            op[1] = o1;
        }
    }
}

extern "C" void kernel_launch(void* const* d_in, const int* in_sizes, int n_in,
                              void* d_out, int out_size, void* d_ws, size_t ws_size,
                              hipStream_t stream) {
    const float* feat_values = (const float*)d_in[0];
    const float* W           = (const float*)d_in[1];
    const float* adj_values  = (const float*)d_in[2];
    const int*   feat_rows   = (const int*)d_in[3];
    const int*   feat_cols   = (const int*)d_in[4];
    const int*   adj_rows    = (const int*)d_in[5];
    const int*   adj_cols    = (const int*)d_in[6];
    float* out = (float*)d_out;

    // ---- workspace layout (bytes) ----
    char* ws = (char*)d_ws;
    int* bcur_x = (int*)(ws + 0);
    int* bcur_a = (int*)(ws + 2048);
    float2* gx  = (float2*)(ws + 204800);
    float2* ga  = (float2*)(ws + 13817856);
    unsigned short* xw = (unsigned short*)(ws + 29833216);

    hipMemsetAsync(ws, 0, 4096, stream);    // bucket cursors

    dim3 gp1((N_EDGES + CHUNK - 1) / CHUNK, 2);
    phase1<<<gp1, 512, 0, stream>>>(feat_values, feat_rows, feat_cols,
                                    adj_values, adj_rows, adj_cols,
                                    bcur_x, bcur_a, gx, ga);
    sort_x_spmm1<<<NB, 1024, 0, stream>>>(bcur_x, gx, W, xw);
    sort_a_spmm2<<<NB, 1024, 0, stream>>>(bcur_a, ga, xw, out);
}